// Round 4
// baseline (34.100 us; speedup 1.0000x reference)
//
#include <hip/hip_runtime.h>

constexpr int N_NODES  = 4000000;
constexpr int N_GRAPHS = 4096;
constexpr int D_FEAT   = 8;
constexpr int N_CLS    = 10;

typedef float f32x4 __attribute__((ext_vector_type(4)));
typedef int   i32x4 __attribute__((ext_vector_type(4)));

// Kernel A: bandwidth-parallel boundary scan (no dependent-load chain).
// bounds[g] = first index i with ids[i] >= g, for g in [0, N_GRAPHS].
// Each thread handles 4 consecutive ids, detects transitions, and writes
// every bound in the gap (handles empty segments too).
__global__ __launch_bounds__(256) void scan_bounds(
    const i32x4* __restrict__ ids4, const int* __restrict__ ids,
    int* __restrict__ bounds)
{
    int t = blockIdx.x * blockDim.x + threadIdx.x;
    int base = t * 4;
    if (base >= N_NODES) return;

    i32x4 v = __builtin_nontemporal_load(ids4 + t);
    int prev = (base == 0) ? -1 : ids[base - 1];  // neighbor's line: L2 hit

    int cur;
    cur = v.x; if (cur != prev) { for (int g = prev + 1; g <= cur; ++g) bounds[g] = base + 0; } prev = cur;
    cur = v.y; if (cur != prev) { for (int g = prev + 1; g <= cur; ++g) bounds[g] = base + 1; } prev = cur;
    cur = v.z; if (cur != prev) { for (int g = prev + 1; g <= cur; ++g) bounds[g] = base + 2; } prev = cur;
    cur = v.w; if (cur != prev) { for (int g = prev + 1; g <= cur; ++g) bounds[g] = base + 3; } prev = cur;

    if (base + 4 >= N_NODES) {  // thread owning the last element closes the tail
        for (int g = prev + 1; g <= N_GRAPHS; ++g) bounds[g] = N_NODES;
    }
}

// Kernel B: one block per graph. Sum x[s:e] (8 feats), mean, then logits.
__global__ __launch_bounds__(256) void pool_linear(
    const f32x4* __restrict__ x4,      // [N_NODES*2] two float4 per node
    const int*   __restrict__ bounds,  // [N_GRAPHS+1]
    const float* __restrict__ W,       // [N_CLS, D_FEAT]
    const float* __restrict__ bias,    // [N_CLS]
    float*       __restrict__ out)     // [N_GRAPHS, N_CLS]
{
    int g = blockIdx.x;
    int s = bounds[g];
    int e = bounds[g + 1];
    int len = e - s;

    f32x4 a0 = (f32x4)(0.f);
    f32x4 a1 = (f32x4)(0.f);

    // Coalesced one-pass stream: nontemporal to keep x out of L2.
    for (int n = s + (int)threadIdx.x; n < e; n += 256) {
        f32x4 v0 = __builtin_nontemporal_load(x4 + 2 * (size_t)n);
        f32x4 v1 = __builtin_nontemporal_load(x4 + 2 * (size_t)n + 1);
        a0 += v0;
        a1 += v1;
    }

    // Wave (64-lane) butterfly reduction of the 8 partial sums.
    #pragma unroll
    for (int off = 32; off > 0; off >>= 1) {
        a0.x += __shfl_xor(a0.x, off);
        a0.y += __shfl_xor(a0.y, off);
        a0.z += __shfl_xor(a0.z, off);
        a0.w += __shfl_xor(a0.w, off);
        a1.x += __shfl_xor(a1.x, off);
        a1.y += __shfl_xor(a1.y, off);
        a1.z += __shfl_xor(a1.z, off);
        a1.w += __shfl_xor(a1.w, off);
    }

    __shared__ float red[4][D_FEAT];
    __shared__ float mean[D_FEAT];
    int wid  = threadIdx.x >> 6;
    int lane = threadIdx.x & 63;
    if (lane == 0) {
        red[wid][0] = a0.x; red[wid][1] = a0.y;
        red[wid][2] = a0.z; red[wid][3] = a0.w;
        red[wid][4] = a1.x; red[wid][5] = a1.y;
        red[wid][6] = a1.z; red[wid][7] = a1.w;
    }
    __syncthreads();
    if (threadIdx.x < D_FEAT) {
        float v = red[0][threadIdx.x] + red[1][threadIdx.x]
                + red[2][threadIdx.x] + red[3][threadIdx.x];
        mean[threadIdx.x] = v / (float)len;
    }
    __syncthreads();
    if (threadIdx.x < N_CLS) {
        const float* w = W + (size_t)threadIdx.x * D_FEAT;
        float acc = bias[threadIdx.x];
        #pragma unroll
        for (int j = 0; j < D_FEAT; ++j)
            acc += mean[j] * w[j];
        out[(size_t)g * N_CLS + threadIdx.x] = acc;
    }
}

extern "C" void kernel_launch(void* const* d_in, const int* in_sizes, int n_in,
                              void* d_out, int out_size, void* d_ws, size_t ws_size,
                              hipStream_t stream) {
    const float* x   = (const float*)d_in[0];   // [4M, 8] f32
    const int*   ids = (const int*)d_in[1];     // [4M] sorted segment ids
    // d_in[2] input_ids, d_in[3] attention_mask: unused by the forward
    const float* W   = (const float*)d_in[4];   // [10, 8]
    const float* b   = (const float*)d_in[5];   // [10]
    float*       out = (float*)d_out;           // [4096, 10]

    int* bounds = (int*)d_ws;                   // [N_GRAPHS+1]

    int scan_threads = N_NODES / 4;             // 1,000,000
    scan_bounds<<<(scan_threads + 255) / 256, 256, 0, stream>>>(
        (const i32x4*)ids, ids, bounds);
    pool_linear<<<N_GRAPHS, 256, 0, stream>>>((const f32x4*)x, bounds, W, b, out);
}

// Round 5
// 29.971 us; speedup vs baseline: 1.1378x; 1.1378x over previous
//
#include <hip/hip_runtime.h>

constexpr int N_NODES  = 4000000;
constexpr int N_GRAPHS = 4096;
constexpr int D_FEAT   = 8;
constexpr int N_CLS    = 10;

typedef float f32x4 __attribute__((ext_vector_type(4)));
typedef int   i32x4 __attribute__((ext_vector_type(4)));

// Kernel A: bandwidth-parallel boundary scan.
// bounds[g] = first index i with ids[i] >= g, for g in [0, N_GRAPHS].
__global__ __launch_bounds__(256) void scan_bounds(
    const i32x4* __restrict__ ids4, const int* __restrict__ ids,
    int* __restrict__ bounds)
{
    int t = blockIdx.x * blockDim.x + threadIdx.x;
    int base = t * 4;
    if (base >= N_NODES) return;

    i32x4 v = __builtin_nontemporal_load(ids4 + t);
    int prev = (base == 0) ? -1 : ids[base - 1];  // neighbor's line: L2 hit

    int cur;
    cur = v.x; if (cur != prev) { for (int g = prev + 1; g <= cur; ++g) bounds[g] = base + 0; } prev = cur;
    cur = v.y; if (cur != prev) { for (int g = prev + 1; g <= cur; ++g) bounds[g] = base + 1; } prev = cur;
    cur = v.z; if (cur != prev) { for (int g = prev + 1; g <= cur; ++g) bounds[g] = base + 2; } prev = cur;
    cur = v.w; if (cur != prev) { for (int g = prev + 1; g <= cur; ++g) bounds[g] = base + 3; } prev = cur;

    if (base + 4 >= N_NODES) {  // thread owning the last element closes the tail
        for (int g = prev + 1; g <= N_GRAPHS; ++g) bounds[g] = N_NODES;
    }
}

// Kernel B: one block per graph. Unit-stride float4 stream over the segment:
// lane i reads float4 (base+i); thread parity fixes which feature-half it
// accumulates (even threads: feats 0-3, odd: feats 4-7).
__global__ __launch_bounds__(256) void pool_linear(
    const f32x4* __restrict__ xf,      // [N_NODES*2] flat float4 view of x
    const int*   __restrict__ bounds,  // [N_GRAPHS+1]
    const float* __restrict__ W,       // [N_CLS, D_FEAT]
    const float* __restrict__ bias,    // [N_CLS]
    float*       __restrict__ out)     // [N_GRAPHS, N_CLS]
{
    int g = blockIdx.x;
    int s = bounds[g];
    int e = bounds[g + 1];
    int len = e - s;
    int nf  = 2 * e;                   // end in float4 units

    f32x4 acc = (f32x4)(0.f);

    // 2x unrolled: two independent 16B loads in flight per iteration.
    for (int i = 2 * s + (int)threadIdx.x; i < nf; i += 512) {
        f32x4 v0 = __builtin_nontemporal_load(xf + i);
        int j = i + 256;
        f32x4 v1;
        bool p = (j < nf);
        if (p) v1 = __builtin_nontemporal_load(xf + j);
        acc += v0;
        if (p) acc += v1;
    }

    // Butterfly over even offsets: sums each parity class separately.
    #pragma unroll
    for (int off = 32; off >= 2; off >>= 1) {
        acc.x += __shfl_xor(acc.x, off);
        acc.y += __shfl_xor(acc.y, off);
        acc.z += __shfl_xor(acc.z, off);
        acc.w += __shfl_xor(acc.w, off);
    }
    // Exchange halves: even lanes hold feats 0-3 in acc, get 4-7 in other.
    f32x4 other;
    other.x = __shfl_xor(acc.x, 1);
    other.y = __shfl_xor(acc.y, 1);
    other.z = __shfl_xor(acc.z, 1);
    other.w = __shfl_xor(acc.w, 1);

    __shared__ float red[4][D_FEAT];
    __shared__ float mean[D_FEAT];
    int wid  = threadIdx.x >> 6;
    int lane = threadIdx.x & 63;
    if (lane == 0) {   // lane 0 is even: acc = low half, other = high half
        red[wid][0] = acc.x;   red[wid][1] = acc.y;
        red[wid][2] = acc.z;   red[wid][3] = acc.w;
        red[wid][4] = other.x; red[wid][5] = other.y;
        red[wid][6] = other.z; red[wid][7] = other.w;
    }
    __syncthreads();
    if (threadIdx.x < D_FEAT) {
        float v = red[0][threadIdx.x] + red[1][threadIdx.x]
                + red[2][threadIdx.x] + red[3][threadIdx.x];
        mean[threadIdx.x] = v / (float)len;
    }
    __syncthreads();
    if (threadIdx.x < N_CLS) {
        const float* w = W + (size_t)threadIdx.x * D_FEAT;
        float a = bias[threadIdx.x];
        #pragma unroll
        for (int j = 0; j < D_FEAT; ++j)
            a += mean[j] * w[j];
        out[(size_t)g * N_CLS + threadIdx.x] = a;
    }
}

extern "C" void kernel_launch(void* const* d_in, const int* in_sizes, int n_in,
                              void* d_out, int out_size, void* d_ws, size_t ws_size,
                              hipStream_t stream) {
    const float* x   = (const float*)d_in[0];   // [4M, 8] f32
    const int*   ids = (const int*)d_in[1];     // [4M] sorted segment ids
    // d_in[2] input_ids, d_in[3] attention_mask: unused by the forward
    const float* W   = (const float*)d_in[4];   // [10, 8]
    const float* b   = (const float*)d_in[5];   // [10]
    float*       out = (float*)d_out;           // [4096, 10]

    int* bounds = (int*)d_ws;                   // [N_GRAPHS+1]

    int scan_threads = N_NODES / 4;             // 1,000,000
    scan_bounds<<<(scan_threads + 255) / 256, 256, 0, stream>>>(
        (const i32x4*)ids, ids, bounds);
    pool_linear<<<N_GRAPHS, 256, 0, stream>>>((const f32x4*)x, bounds, W, b, out);
}